// Round 6
// baseline (186.345 us; speedup 1.0000x reference)
//
#include <hip/hip_runtime.h>

#define BLOCK 256

typedef float f4u __attribute__((ext_vector_type(4), aligned(4)));  // 4B-aligned float4

// R6: TWO waves per sample (8192 waves = 32/CU, full residency), interleaved
// chunk split within a sample, no alignment prologue (4B-aligned dwordx4 is
// exact per R3-R5), one atomicAdd per block. Discriminates "real kernel time"
// vs "harness floor": if total doesn't move with 2x parallelism, we're done.
__global__ __launch_bounds__(BLOCK, 8) void chi2_fused(
    const float* __restrict__ fluct,
    const float* __restrict__ ivar,
    const float* __restrict__ outp,
    const int*  __restrict__ ovl,      // (B,4) int32: s_in, e_in, s_out, e_out
    float* __restrict__ out,           // single f32, pre-zeroed
    int L, float inv_B)
{
    const int gwave = (blockIdx.x * BLOCK + threadIdx.x) >> 6;
    const int lane  = threadIdx.x & 63;
    const int b     = gwave >> 1;          // sample
    const int h     = gwave & 1;           // half (0/1)

    const int4 o   = reinterpret_cast<const int4*>(ovl)[b];  // one dwordx4
    const int s_in = o.x, e_in = o.y, s_out = o.z;
    const int len  = e_in - s_in;

    const float* __restrict__ xp = fluct + (size_t)b * L + s_in;
    const float* __restrict__ wp = ivar  + (size_t)b * L + s_in;
    const float* __restrict__ yp = outp  + (size_t)b * L + s_out;

    const int n4 = len >> 2;               // full 16B chunks (all 4B-aligned)

    float a0 = 0.f, a1 = 0.f;
    int c = lane + (h << 6);               // interleave halves: wave h owns
                                           // chunks congruent to [64h,64h+64)
    // Main: 2 chunks x 3 streams = 6 wide loads in flight, unrolled x2.
    for (; c + 128 < n4; c += 256) {
        const f4u xv0 = *reinterpret_cast<const f4u*>(xp + 4 * c);
        const f4u xv1 = *reinterpret_cast<const f4u*>(xp + 4 * (c + 128));
        const f4u yv0 = *reinterpret_cast<const f4u*>(yp + 4 * c);
        const f4u yv1 = *reinterpret_cast<const f4u*>(yp + 4 * (c + 128));
        const f4u wv0 = *reinterpret_cast<const f4u*>(wp + 4 * c);
        const f4u wv1 = *reinterpret_cast<const f4u*>(wp + 4 * (c + 128));
        #pragma unroll
        for (int e = 0; e < 4; ++e) {
            const float d0 = xv0[e] - yv0[e];
            const float d1 = xv1[e] - yv1[e];
            a0 = fmaf(d0 * d0, wv0[e], a0);
            a1 = fmaf(d1 * d1, wv1[e], a1);
        }
    }
    // Remainder chunks for this wave.
    for (; c < n4; c += 128) {
        const f4u xv = *reinterpret_cast<const f4u*>(xp + 4 * c);
        const f4u yv = *reinterpret_cast<const f4u*>(yp + 4 * c);
        const f4u wv = *reinterpret_cast<const f4u*>(wp + 4 * c);
        #pragma unroll
        for (int e = 0; e < 4; ++e) {
            const float d = xv[e] - yv[e];
            a0 = fmaf(d * d, wv[e], a0);
        }
    }
    // Scalar tail (0..3 elements), handled by the h==1 wave.
    if (h) {
        const int done = n4 << 2;
        if (lane < (len & 3)) {
            const float d = xp[done + lane] - yp[done + lane];
            a0 = fmaf(d * d, wp[done + lane], a0);
        }
    }

    float acc = a0 + a1;

    // wave reduction
    #pragma unroll
    for (int off = 32; off > 0; off >>= 1)
        acc += __shfl_down(acc, off, 64);

    // block reduction: 4 wave-leaders (2 samples' halves) -> LDS -> 1 atomic.
    __shared__ float sacc[BLOCK / 64];
    if (lane == 0) sacc[threadIdx.x >> 6] = (acc / (float)len) * inv_B;
    __syncthreads();

    if (threadIdx.x == 0) {
        float s = 0.f;
        #pragma unroll
        for (int i = 0; i < BLOCK / 64; ++i) s += sacc[i];
        atomicAdd(out, s);
    }
}

extern "C" void kernel_launch(void* const* d_in, const int* in_sizes, int n_in,
                              void* d_out, int out_size, void* d_ws, size_t ws_size,
                              hipStream_t stream) {
    const float* fluct = (const float*)d_in[0];  // (B,1,L) f32
    const float* ivar  = (const float*)d_in[1];  // (B,1,L) f32
    const float* outp  = (const float*)d_in[2];  // (B,1,L) f32
    const int*   ovl   = (const int*)d_in[3];    // (B,4)   i32

    const int B = in_sizes[3] / 4;               // 4096
    const int L = in_sizes[0] / B;               // 4096

    // d_out is poisoned 0xAA before every timed call -> zero it (capturable).
    hipMemsetAsync(d_out, 0, sizeof(float) * out_size, stream);

    const int waves_per_block = BLOCK / 64;
    const int total_waves = B * 2;               // 2 waves per sample
    chi2_fused<<<total_waves / waves_per_block, BLOCK, 0, stream>>>(
        fluct, ivar, outp, ovl, (float*)d_out, L, 1.0f / (float)B);
}

// Round 7
// 172.528 us; speedup vs baseline: 1.0801x; 1.0801x over previous
//
#include <hip/hip_runtime.h>

#define BLOCK 256

typedef float f4u __attribute__((ext_vector_type(4), aligned(4)));  // 4B-aligned float4

// R7: R4/R5 structure + NONTEMPORAL loads. Every input byte is read exactly
// once (windows never overlap across samples' uses), so L1/L2 allocation is
// pure overhead -> nt loads. One wave per sample, 12 wide loads in flight,
// fused block-reduce + one atomicAdd per block.
__device__ __forceinline__ f4u ntload(const float* p) {
    return __builtin_nontemporal_load(reinterpret_cast<const f4u*>(p));
}

__global__ __launch_bounds__(BLOCK) void chi2_fused(
    const float* __restrict__ fluct,
    const float* __restrict__ ivar,
    const float* __restrict__ outp,
    const int*  __restrict__ ovl,      // (B,4) int32: s_in, e_in, s_out, e_out
    float* __restrict__ out,           // single f32, pre-zeroed
    int L, float inv_B)
{
    const int wave = (blockIdx.x * BLOCK + threadIdx.x) >> 6;  // = sample
    const int lane = threadIdx.x & 63;

    const int4 o   = reinterpret_cast<const int4*>(ovl)[wave];
    const int s_in = o.x, e_in = o.y, s_out = o.z;
    const int len  = e_in - s_in;

    const float* __restrict__ xp = fluct + (size_t)wave * L + s_in;
    const float* __restrict__ wp = ivar  + (size_t)wave * L + s_in;
    const float* __restrict__ yp = outp  + (size_t)wave * L + s_out;

    const int n4 = len >> 2;               // full dwordx4 chunks, 4B-aligned

    float a0 = 0.f, a1 = 0.f, a2 = 0.f, a3 = 0.f;
    int c = lane;
    // Main: 4 chunks x 3 streams = 12 nontemporal wide loads in flight.
    for (; c + 192 < n4; c += 256) {
        const f4u xv0 = ntload(xp + 4 * c);
        const f4u xv1 = ntload(xp + 4 * (c +  64));
        const f4u xv2 = ntload(xp + 4 * (c + 128));
        const f4u xv3 = ntload(xp + 4 * (c + 192));
        const f4u yv0 = ntload(yp + 4 * c);
        const f4u yv1 = ntload(yp + 4 * (c +  64));
        const f4u yv2 = ntload(yp + 4 * (c + 128));
        const f4u yv3 = ntload(yp + 4 * (c + 192));
        const f4u wv0 = ntload(wp + 4 * c);
        const f4u wv1 = ntload(wp + 4 * (c +  64));
        const f4u wv2 = ntload(wp + 4 * (c + 128));
        const f4u wv3 = ntload(wp + 4 * (c + 192));
        #pragma unroll
        for (int e = 0; e < 4; ++e) {
            const float d0 = xv0[e] - yv0[e];
            const float d1 = xv1[e] - yv1[e];
            const float d2 = xv2[e] - yv2[e];
            const float d3 = xv3[e] - yv3[e];
            a0 = fmaf(d0 * d0, wv0[e], a0);
            a1 = fmaf(d1 * d1, wv1[e], a1);
            a2 = fmaf(d2 * d2, wv2[e], a2);
            a3 = fmaf(d3 * d3, wv3[e], a3);
        }
    }
    // Remainder chunks.
    for (; c < n4; c += 64) {
        const f4u xv = ntload(xp + 4 * c);
        const f4u yv = ntload(yp + 4 * c);
        const f4u wv = ntload(wp + 4 * c);
        #pragma unroll
        for (int e = 0; e < 4; ++e) {
            const float d = xv[e] - yv[e];
            a0 = fmaf(d * d, wv[e], a0);
        }
    }
    // Scalar tail (0..3 elements).
    const int done = n4 << 2;
    if (lane < (len & 3)) {
        const float d = xp[done + lane] - yp[done + lane];
        a0 = fmaf(d * d, wp[done + lane], a0);
    }

    float acc = (a0 + a1) + (a2 + a3);

    // wave reduction
    #pragma unroll
    for (int off = 32; off > 0; off >>= 1)
        acc += __shfl_down(acc, off, 64);

    // block reduction: 4 wave-leaders -> LDS -> one atomic per block.
    __shared__ float sacc[BLOCK / 64];
    if (lane == 0) sacc[threadIdx.x >> 6] = (acc / (float)len) * inv_B;
    __syncthreads();

    if (threadIdx.x == 0) {
        float s = 0.f;
        #pragma unroll
        for (int i = 0; i < BLOCK / 64; ++i) s += sacc[i];
        atomicAdd(out, s);
    }
}

extern "C" void kernel_launch(void* const* d_in, const int* in_sizes, int n_in,
                              void* d_out, int out_size, void* d_ws, size_t ws_size,
                              hipStream_t stream) {
    const float* fluct = (const float*)d_in[0];  // (B,1,L) f32
    const float* ivar  = (const float*)d_in[1];  // (B,1,L) f32
    const float* outp  = (const float*)d_in[2];  // (B,1,L) f32
    const int*   ovl   = (const int*)d_in[3];    // (B,4)   i32

    const int B = in_sizes[3] / 4;               // 4096
    const int L = in_sizes[0] / B;               // 4096

    // d_out is poisoned 0xAA before every timed call -> zero it (capturable).
    hipMemsetAsync(d_out, 0, sizeof(float) * out_size, stream);

    const int waves_per_block = BLOCK / 64;      // 4
    chi2_fused<<<B / waves_per_block, BLOCK, 0, stream>>>(
        fluct, ivar, outp, ovl, (float*)d_out, L, 1.0f / (float)B);
}